// Round 2
// baseline (666.765 us; speedup 1.0000x reference)
//
#include <hip/hip_runtime.h>

#define S 512
#define NB 8          // batch
#define KT 256        // k-tile per block
#define JT 32         // j-tile per staging round
#define WT_STRIDE 257 // KT+1: de-aliases banks for the transposed W store

// Workspace layout (harness zero-fills d_ws each iteration; we overwrite all we read):
//   Diag[i][j][b] : S*S*NB floats (8 MB) at ws + 0       ; Diag[i][j][b] = x[b][j][i-j], 0 for j>i
//   Res [i][k][b] : S*S*NB floats (8 MB) at ws + S*S*NB  ; Res[i][k][b]  = out_ref[b][i][k]

// ---------------------------------------------------------------------------
// K1: tiled transpose-gather x -> Diag. Both sides segment-coalesced via LDS.
// ---------------------------------------------------------------------------
__global__ __launch_bounds__(256) void gather_diag_kernel(const float* __restrict__ x,
                                                          float* __restrict__ Diag) {
  __shared__ float T[32 * 32 * NB];          // [il][jl][b], 32 KB
  const int i0 = blockIdx.x * 32;
  const int j0 = blockIdx.y * 32;
  const int t  = threadIdx.x;
  const int jl = t >> 3;                     // 0..31
  const int b  = t & 7;
  const int j  = j0 + jl;

  // read: thread walks 32 consecutive x elements of row (b, j); LDS store is
  // bank-free: (8*jl + b) spans lanes -> 2-way max.
  const float* xr = x + (size_t)b * (S * S) + (size_t)j * S;
  const int cbase = i0 - j;                  // c = i - j, i = i0 + m
#pragma unroll
  for (int m = 0; m < 32; ++m) {
    const int c = cbase + m;
    T[m * (32 * NB) + jl * NB + b] = (c >= 0) ? xr[c] : 0.0f;
  }
  __syncthreads();

  // write: Diag rows are contiguous 256-float runs -> float4, fully coalesced.
  const int row0 = t >> 6;                   // 0..3
  const int f4   = t & 63;                   // 0..63
#pragma unroll
  for (int p = 0; p < 8; ++p) {
    const int row = p * 4 + row0;
    const float4 v = *(const float4*)&T[row * (32 * NB) + 4 * f4];
    *(float4*)(Diag + (size_t)(i0 + row) * (S * NB) + j0 * NB + 4 * f4) = v;
  }
}

// ---------------------------------------------------------------------------
// K2: per-diagonal Linear. One block per (diagonal i, k-tile of 256).
// W loader: wave reads 8 rows x 128 B contiguous segments per instruction
// (16 lines/instr instead of 64 with the old lane<->row mapping).
// ---------------------------------------------------------------------------
__global__ __launch_bounds__(256, 3) void diag_linear_kernel(const float* __restrict__ Diag,
                                                             const float* __restrict__ W,
                                                             const float* __restrict__ bias,
                                                             float* __restrict__ Res) {
  __shared__ __align__(16) float WtBuf[JT * WT_STRIDE]; // 32.9 KB; reused as Racc at end
  __shared__ __align__(16) float DlBuf[S * NB];         // 16 KB

  const int i  = (S - 1) - (int)blockIdx.x;  // big diagonals first
  const int k0 = (int)blockIdx.y * KT;
  if (k0 > i) return;                        // uniform exit, before any barrier

  const int tid  = threadIdx.x;
  const int wave = tid >> 6;
  const int lane = tid & 63;

  const int jend = (i + JT) & ~(JT - 1);     // roundup(i+1, JT)

  // ---- stage D: fully coalesced float4 copy from Diag[i] (zeros pre-padded) ----
  {
    const float4* src = (const float4*)(Diag + (size_t)i * (S * NB));
    float4*       dst = (float4*)DlBuf;
    for (int idx = tid; idx < jend * 2; idx += 256) dst[idx] = src[idx];
  }

  float acc[4][NB];
#pragma unroll
  for (int m = 0; m < 4; ++m)
#pragma unroll
    for (int b = 0; b < NB; ++b) acc[m][b] = 0.0f;

  // loader mapping: thread t covers row-sub (t>>3) in 0..31 and j-sub 4*(t&7);
  // load q hits row k0 + 32q + (t>>3). Per wave instruction: 8 rows x 128 B.
  const int rsub = tid >> 3;
  const int jsub = 4 * (tid & 7);
  const float* wbase = W + ((size_t)i * S + (size_t)(k0 + rsub)) * S + jsub;

  bool rok[8];
#pragma unroll
  for (int q = 0; q < 8; ++q) rok[q] = (k0 + 32 * q + rsub) <= i; // rows k>i are zero: skip

  // preload tile 0
  float4 v[8];
#pragma unroll
  for (int q = 0; q < 8; ++q)
    v[q] = rok[q] ? *(const float4*)(wbase + (size_t)q * (32 * S))
                  : make_float4(0.f, 0.f, 0.f, 0.f);

  for (int j0 = 0; j0 < jend; j0 += JT) {
    __syncthreads();                         // previous tile's compute done; Wt free
    // transposed store Wt[jsub+m][32q + rsub]; stride 257 => banks
    // (4(t&7)+m + (t>>3)) mod 32 -> <=2-way (free).
#pragma unroll
    for (int q = 0; q < 8; ++q) {
      const int kl = 32 * q + rsub;
      WtBuf[(jsub + 0) * WT_STRIDE + kl] = v[q].x;
      WtBuf[(jsub + 1) * WT_STRIDE + kl] = v[q].y;
      WtBuf[(jsub + 2) * WT_STRIDE + kl] = v[q].z;
      WtBuf[(jsub + 3) * WT_STRIDE + kl] = v[q].w;
    }
    // software pipeline: issue next tile's loads before computing this one
    const int jn = j0 + JT;
    if (jn < jend) {
#pragma unroll
      for (int q = 0; q < 8; ++q)
        if (rok[q]) v[q] = *(const float4*)(wbase + (size_t)q * (32 * S) + jn);
    }
    __syncthreads();                         // Wt (and Dl on first iter) visible

    // compute core: UNCHANGED (same math order as the 653 µs kernel)
#pragma unroll
    for (int u = 0; u < 8; ++u) {
      const int jl = (wave << 3) + u;
      const float4 wv = *(const float4*)&WtBuf[jl * WT_STRIDE + (lane << 2)]; // conflict-free b128
      const float4 dA = *(const float4*)&DlBuf[(j0 + jl) * NB];               // broadcast
      const float4 dB = *(const float4*)&DlBuf[(j0 + jl) * NB + 4];           // broadcast
      const float wm[4] = {wv.x, wv.y, wv.z, wv.w};
#pragma unroll
      for (int m = 0; m < 4; ++m) {
        acc[m][0] = fmaf(wm[m], dA.x, acc[m][0]);
        acc[m][1] = fmaf(wm[m], dA.y, acc[m][1]);
        acc[m][2] = fmaf(wm[m], dA.z, acc[m][2]);
        acc[m][3] = fmaf(wm[m], dA.w, acc[m][3]);
        acc[m][4] = fmaf(wm[m], dB.x, acc[m][4]);
        acc[m][5] = fmaf(wm[m], dB.y, acc[m][5]);
        acc[m][6] = fmaf(wm[m], dB.z, acc[m][6]);
        acc[m][7] = fmaf(wm[m], dB.w, acc[m][7]);
      }
    }
  }

  __syncthreads();                           // all compute done; Wt reusable as Racc
  float* Racc = WtBuf;                       // Racc[b*KT + k_local] (2048 floats fit)

  // cross-wave reduction (waves split j, each holds partials for all k)
  for (int w = 0; w < 4; ++w) {
    if (wave == w) {
#pragma unroll
      for (int b = 0; b < NB; ++b) {
        float4* p = (float4*)&Racc[b * KT + (lane << 2)];
        float4 cur = make_float4(acc[0][b], acc[1][b], acc[2][b], acc[3][b]);
        if (w != 0) {
          float4 old = *p;
          cur.x += old.x; cur.y += old.y; cur.z += old.z; cur.w += old.w;
        }
        *p = cur;
      }
    }
    __syncthreads();
  }

  // epilogue: bias + CONTIGUOUS Res[i][k0..k0+256][0..8) write (float4, coalesced).
  // k>i entries are 0+0 and never read by K3 (bias is masked to 0 there too).
  {
    float4* dst = (float4*)(Res + ((size_t)i * S + k0) * NB);
    for (int idx = tid; idx < 512; idx += 256) {
      const int kl = idx >> 1;
      const int h  = (idx & 1) * 4;
      const float bv = bias[(size_t)i * S + k0 + kl];
      float4 o;
      o.x = Racc[(h + 0) * KT + kl] + bv;
      o.y = Racc[(h + 1) * KT + kl] + bv;
      o.z = Racc[(h + 2) * KT + kl] + bv;
      o.w = Racc[(h + 3) * KT + kl] + bv;
      dst[idx] = o;
    }
  }
}

// ---------------------------------------------------------------------------
// K3: tiled scatter Res -> out, absorbs the tail copy (r+c >= S : out = x).
// FIX vs round 1: phase B now covers all 32 columns (was cl = (t&63)>>3, which
// wrote only columns 0..7 of each tile -> 3/4 of out stayed zero).
// ---------------------------------------------------------------------------
__global__ __launch_bounds__(256) void scatter_out_kernel(const float* __restrict__ x,
                                                          const float* __restrict__ Res,
                                                          float* __restrict__ out) {
  __shared__ float T[32 * 32 * NB];          // [rl][cl][b], 32 KB
  const int r0 = blockIdx.x * 32;
  const int c0 = blockIdx.y * 32;
  const int t  = threadIdx.x;
  const int cl = t >> 3;                     // 0..31
  const int b  = t & 7;

  if (r0 + c0 < S) {
    // phase A: T[rl][cl][b] = Res[(r0+rl)+(c0+cl)][c0+cl][b]
    // lanes cover (cl,b): 8 x 32 B segments per instr; LDS store 2-way (free).
#pragma unroll 4
    for (int p = 0; p < 32; ++p) {
      const int ii = r0 + p + c0 + cl;
      if (ii < S)
        T[p * 256 + t] = Res[((size_t)ii * S + (c0 + cl)) * NB + b];
    }
  }
  __syncthreads();

  // phase B: one row per iteration; 256 threads cover (cl 0..31, b 0..7).
  // Per wave instruction: 8 batches x 32 B segments. LDS read 2-way (free).
#pragma unroll 8
  for (int r = 0; r < 32; ++r) {
    const int gr = r0 + r;
    const int gc = c0 + cl;
    const size_t o = (size_t)b * (S * S) + (size_t)gr * S + gc;
    out[o] = (gr + gc < S) ? T[r * 256 + t] : x[o];
  }
}

extern "C" void kernel_launch(void* const* d_in, const int* in_sizes, int n_in,
                              void* d_out, int out_size, void* d_ws, size_t ws_size,
                              hipStream_t stream) {
  const float* x    = (const float*)d_in[0];
  const float* W    = (const float*)d_in[1];
  const float* bias = (const float*)d_in[2];
  float* out = (float*)d_out;

  float* Diag = (float*)d_ws;
  float* Res  = (float*)d_ws + (size_t)S * S * NB;   // needs 16 MB of workspace

  (void)ws_size; (void)in_sizes; (void)n_in; (void)out_size;

  gather_diag_kernel<<<dim3(S / 32, S / 32), 256, 0, stream>>>(x, Diag);
  diag_linear_kernel<<<dim3(S, 2), 256, 0, stream>>>(Diag, W, bias, Res);
  scatter_out_kernel<<<dim3(S / 32, S / 32), 256, 0, stream>>>(x, Res, out);
}

// Round 3
// 657.036 us; speedup vs baseline: 1.0148x; 1.0148x over previous
//
#include <hip/hip_runtime.h>

#define S 512
#define NB 8          // batch
#define KT 256        // k-tile per block
#define JT 32         // j-tile per staging round
#define WT_STRIDE 257 // KT+1: transposed-store banks = (4*(t&7)+m+(t>>3))%32 -> <=2-way (free)

// Copy the untouched region: out[b,r,c] = x[b,r,c] for r+c >= S.
__global__ __launch_bounds__(256) void tail_copy_kernel(const float* __restrict__ x,
                                                        float* __restrict__ out) {
  int idx = blockIdx.x * 256 + threadIdx.x;
  int c = idx & (S - 1);
  int r = (idx >> 9) & (S - 1);
  if (r + c >= S) out[idx] = x[idx];
}

// One block per (diagonal i, k-tile). Computes out[b, i-k, k] for k in tile.
__global__ __launch_bounds__(256, 3) void diag_linear_kernel(const float* __restrict__ x,
                                                             const float* __restrict__ W,
                                                             const float* __restrict__ bias,
                                                             float* __restrict__ out) {
  // Wt[j][k] transposed W tile (32.9 KB), reused as Racc[b][k] (8 KB) at the end.
  __shared__ __align__(16) float WtBuf[JT * WT_STRIDE];
  // Dl[j][b]: gathered diagonal of x (16 KB).
  __shared__ __align__(16) float DlBuf[S * NB];

  const int i  = (S - 1) - (int)blockIdx.x;   // big diagonals first
  const int k0 = (int)blockIdx.y * KT;
  if (k0 > i) return;                          // uniform exit, before any barrier

  const int tid  = threadIdx.x;
  const int wave = tid >> 6;
  const int lane = tid & 63;

  const int jend = (i + JT) & ~(JT - 1);       // roundup(i+1, JT)

  // ---- stage D: Dl[j][b] = x[b, j, i-j] for j<=i, else 0 (zero-fill padding) ----
  for (int idx = tid; idx < jend * NB; idx += 256) {
    const int j = idx >> 3;
    const int b = idx & 7;
    DlBuf[idx] = (j <= i) ? x[b * (S * S) + j * S + (i - j)] : 0.0f;
  }

  float acc[4][NB];
#pragma unroll
  for (int m = 0; m < 4; ++m)
#pragma unroll
    for (int b = 0; b < NB; ++b) acc[m][b] = 0.0f;

  // Coalesced W loader: thread t covers row-sub (t>>3) and j-sub 4*(t&7);
  // load q hits row k0 + 32q + (t>>3). Per wave instruction: 8 rows x 128 B
  // contiguous segments = 16 cache lines (vs 64 with the lane<->row mapping).
  const int rsub = tid >> 3;
  const int jsub = 4 * (tid & 7);
  const float* wbase = W + ((size_t)i * S + (size_t)(k0 + rsub)) * S + jsub;

  bool rok[8];
#pragma unroll
  for (int q = 0; q < 8; ++q) rok[q] = (k0 + 32 * q + rsub) <= i; // rows k>i are zero: skip

  // preload tile 0
  float4 v[8];
#pragma unroll
  for (int q = 0; q < 8; ++q)
    v[q] = rok[q] ? *(const float4*)(wbase + (size_t)q * (32 * S))
                  : make_float4(0.f, 0.f, 0.f, 0.f);

  for (int j0 = 0; j0 < jend; j0 += JT) {
    __syncthreads();                           // previous tile's compute done; Wt free
    // transposed store Wt[jsub+m][32q + rsub]
#pragma unroll
    for (int q = 0; q < 8; ++q) {
      const int kl = 32 * q + rsub;
      WtBuf[(jsub + 0) * WT_STRIDE + kl] = v[q].x;
      WtBuf[(jsub + 1) * WT_STRIDE + kl] = v[q].y;
      WtBuf[(jsub + 2) * WT_STRIDE + kl] = v[q].z;
      WtBuf[(jsub + 3) * WT_STRIDE + kl] = v[q].w;
    }
    // software pipeline: issue next tile's global loads before computing this one
    const int jn = j0 + JT;
    if (jn < jend) {
#pragma unroll
      for (int q = 0; q < 8; ++q)
        if (rok[q]) v[q] = *(const float4*)(wbase + (size_t)q * (32 * S) + jn);
    }
    __syncthreads();                           // Wt (and Dl on first iter) visible

    // compute core: UNCHANGED math order (absmax-stable since round 0)
#pragma unroll
    for (int u = 0; u < 8; ++u) {
      const int jl = (wave << 3) + u;
      const float4 wv = *(const float4*)&WtBuf[jl * WT_STRIDE + (lane << 2)]; // conflict-free b128
      const float4 dA = *(const float4*)&DlBuf[(j0 + jl) * NB];               // broadcast
      const float4 dB = *(const float4*)&DlBuf[(j0 + jl) * NB + 4];           // broadcast
      const float wm[4] = {wv.x, wv.y, wv.z, wv.w};
#pragma unroll
      for (int m = 0; m < 4; ++m) {
        acc[m][0] = fmaf(wm[m], dA.x, acc[m][0]);
        acc[m][1] = fmaf(wm[m], dA.y, acc[m][1]);
        acc[m][2] = fmaf(wm[m], dA.z, acc[m][2]);
        acc[m][3] = fmaf(wm[m], dA.w, acc[m][3]);
        acc[m][4] = fmaf(wm[m], dB.x, acc[m][4]);
        acc[m][5] = fmaf(wm[m], dB.y, acc[m][5]);
        acc[m][6] = fmaf(wm[m], dB.z, acc[m][6]);
        acc[m][7] = fmaf(wm[m], dB.w, acc[m][7]);
      }
    }
  }

  __syncthreads();                             // all compute done; Wt reusable as Racc
  float* Racc = WtBuf;                         // Racc[b*KT + k_local]

  // cross-wave reduction (waves split j, so each holds partials for all k)
  for (int w = 0; w < 4; ++w) {
    if (wave == w) {
#pragma unroll
      for (int b = 0; b < NB; ++b) {
        float4* p = (float4*)&Racc[b * KT + (lane << 2)];
        float4 cur = make_float4(acc[0][b], acc[1][b], acc[2][b], acc[3][b]);
        if (w != 0) {
          float4 old = *p;
          cur.x += old.x; cur.y += old.y; cur.z += old.z; cur.w += old.w;
        }
        *p = cur;
      }
    }
    __syncthreads();
  }

  // epilogue: bias + scatter out[b, i-k, k]
  if ((k0 + tid) <= i) {
    const int k = k0 + tid;
    const float bv = bias[i * S + k];
    const int r = i - k;
#pragma unroll
    for (int b = 0; b < NB; ++b)
      out[b * (S * S) + r * S + k] = Racc[b * KT + tid] + bv;
  }
}

extern "C" void kernel_launch(void* const* d_in, const int* in_sizes, int n_in,
                              void* d_out, int out_size, void* d_ws, size_t ws_size,
                              hipStream_t stream) {
  const float* x    = (const float*)d_in[0];
  const float* W    = (const float*)d_in[1];
  const float* bias = (const float*)d_in[2];
  float* out = (float*)d_out;

  (void)d_ws; (void)ws_size; (void)in_sizes; (void)n_in; (void)out_size;

  tail_copy_kernel<<<dim3((NB * S * S) / 256), 256, 0, stream>>>(x, out);
  diag_linear_kernel<<<dim3(S, 2), 256, 0, stream>>>(x, W, bias, out);
}